// Round 1
// baseline (125.796 us; speedup 1.0000x reference)
//
#include <hip/hip_runtime.h>

// ChamferDistance2D: B=8, N=M=8192, fp32, scalar output.
// cost = sum_b [ mean_i min_j d(i,j) + mean_j min_i d(i,j) ],  d = squared L2.
// d(i,j) = |p1_i|^2 + (|p2_j|^2 - 2 p1_i . p2_j); store min_j of the paren term.
//
// R9: occupancy + register-pressure round. R8's counters showed
// VGPR_Count=44 (< the 48 live floats of m/xp/yp alone) => compiler pushed
// state into AGPRs with v_accvgpr shuttle traffic (true VALUBusy ~56% after
// halving the gfx94x-formula 113%, at only ~2.3 waves/SIMD occupancy).
// Fix: IPT 16->8 and j-unroll 8->4 cuts live state to ~55 regs (fits 64),
// TILES 2->4 doubles grid to 2048 = 8 blocks/CU = 8 waves/SIMD, forced via
// __launch_bounds__(256,8). LDS latency now TLP-hidden; no shuttles.
// Per pair-dir cost unchanged: 2 v_fma_f32 + 0.5 v_min3_f32 (floor ~35us).
// LDS pipe at 32 waves/CU: 1 broadcast ds_read_b128 per 8 pairs ~60% busy.

#define BATCH 8
#define NPTS  8192
#define TPB   256
#define IPT   8
#define PPB   (TPB * IPT)     // 2048
#define TILES (NPTS / PPB)    // 4
#define S     32              // j-splits
#define JCH   (NPTS / S)      // 256 j's per block

__device__ inline float min3f(float a, float b, float c) {
    float d;
    asm("v_min3_f32 %0, %1, %2, %3" : "=v"(d) : "v"(a), "v"(b), "v"(c));
    return d;
}

// grid.x = 2 * BATCH * TILES * S = 2048
__global__ __launch_bounds__(TPB, 8)
void chamfer_partial(const float* __restrict__ p1, const float* __restrict__ p2,
                     float* __restrict__ partial /* [2][B][S][N] */,
                     float* __restrict__ out_to_zero) {
    __shared__ float4 q[JCH];      // (x, y, |p|^2, pad)

    if (blockIdx.x == 0 && threadIdx.x == 0) *out_to_zero = 0.0f;

    int blk   = blockIdx.x;
    int split = blk & (S - 1);      blk >>= 5;
    int tile  = blk & (TILES - 1);  blk >>= 2;
    int b     = blk & (BATCH - 1);  blk >>= 3;
    int dir   = blk;

    const float2* a  = (const float2*)(dir ? p2 : p1) + (size_t)b * NPTS;
    const float2* bp = (const float2*)(dir ? p1 : p2) + (size_t)b * NPTS + split * JCH;

    int t = threadIdx.x;

    for (int j = t; j < JCH; j += TPB) {
        float2 v = bp[j];
        q[j] = make_float4(v.x, v.y, fmaf(v.x, v.x, v.y * v.y), 0.0f);
    }

    int pt_base = tile * PPB;
    float xp[IPT], yp[IPT], m[IPT];
#pragma unroll
    for (int k = 0; k < IPT; ++k) {
        float2 v = a[pt_base + k * TPB + t];
        xp[k] = -2.0f * v.x;
        yp[k] = -2.0f * v.y;
        m[k]  = 3.0e38f;
    }

    __syncthreads();

    // unroll-4, direct q[] reads: 4 broadcast ds_read_b128 feed 8x4 = 32
    // pairs of math; at 8 waves/SIMD the LDS latency is TLP-hidden.
    for (int j = 0; j < JCH; j += 4) {
        float4 q0 = q[j + 0], q1 = q[j + 1], q2 = q[j + 2], q3 = q[j + 3];
#pragma unroll
        for (int k = 0; k < IPT; ++k) {
            float t0 = fmaf(yp[k], q0.y, fmaf(xp[k], q0.x, q0.z));
            float t1 = fmaf(yp[k], q1.y, fmaf(xp[k], q1.x, q1.z));
            float t2 = fmaf(yp[k], q2.y, fmaf(xp[k], q2.x, q2.z));
            float t3 = fmaf(yp[k], q3.y, fmaf(xp[k], q3.x, q3.z));
            m[k] = min3f(m[k], t0, t1);
            m[k] = min3f(m[k], t2, t3);
        }
    }

    float* outp = partial + ((size_t)((dir * BATCH + b) * S + split)) * NPTS + pt_base;
#pragma unroll
    for (int k = 0; k < IPT; ++k)
        outp[k * TPB + t] = m[k];
}

// grid.x = 2 * BATCH * NPTS / TPB = 512
__global__ __launch_bounds__(TPB)
void chamfer_reduce(const float* __restrict__ p1, const float* __restrict__ p2,
                    const float* __restrict__ partial, float* __restrict__ out) {
    int gid   = blockIdx.x * TPB + threadIdx.x;
    int point = gid & (NPTS - 1);
    int rest  = gid >> 13;
    int b     = rest & (BATCH - 1);
    int dir   = rest >> 3;

    const float* base = partial + ((size_t)(dir * BATCH + b) * S) * NPTS + point;
    float m = base[0];
#pragma unroll
    for (int s = 1; s < S; ++s)
        m = fminf(m, base[(size_t)s * NPTS]);

    float2 v = ((const float2*)(dir ? p2 : p1))[(size_t)b * NPTS + point];
    float d = m + fmaf(v.x, v.x, v.y * v.y);

#pragma unroll
    for (int off = 32; off > 0; off >>= 1)
        d += __shfl_down(d, off, 64);

    __shared__ float wsum[TPB / 64];
    int lane = threadIdx.x & 63;
    int w    = threadIdx.x >> 6;
    if (lane == 0) wsum[w] = d;
    __syncthreads();
    if (threadIdx.x == 0) {
        float ssum = wsum[0] + wsum[1] + wsum[2] + wsum[3];
        atomicAdd(out, ssum * (1.0f / NPTS));
    }
}

extern "C" void kernel_launch(void* const* d_in, const int* in_sizes, int n_in,
                              void* d_out, int out_size, void* d_ws, size_t ws_size,
                              hipStream_t stream) {
    const float* p1 = (const float*)d_in[0];
    const float* p2 = (const float*)d_in[1];
    float* out      = (float*)d_out;
    float* partial  = (float*)d_ws;   // needs 2*8*32*8192*4 = 16 MB (32 MB proven in R2)

    chamfer_partial<<<2 * BATCH * TILES * S, TPB, 0, stream>>>(p1, p2, partial, out);
    chamfer_reduce<<<2 * BATCH * NPTS / TPB, TPB, 0, stream>>>(p1, p2, partial, out);
}

// Round 2
// 115.902 us; speedup vs baseline: 1.0854x; 1.0854x over previous
//
#include <hip/hip_runtime.h>

// ChamferDistance2D: B=8, N=M=8192, fp32, scalar output.
// cost = sum_b [ mean_i min_j d(i,j) + mean_j min_i d(i,j) ],  d = squared L2.
// d(i,j) = |p1_i|^2 + (|p2_j|^2 - 2 p1_i . p2_j); store min_j of the paren term.
//
// R10: packed-fp32 round. R8 vs R9 proved partial is VALU-issue-bound
// (64.2us at BOTH 4 and 8 waves/SIMD, VALUBusy pinned ~110 gfx94x-formula):
// occupancy is a dead lever; instruction count is the only one left.
// v_pk_fma_f32 (CDNA double-rate packed fp32) packs 2 j's per inst:
// per 2 pairs = 2 pk_fma + 1 min3 -> 1.56 insts/pair vs 2.5 (x0.625).
// Requires SoA LDS (qx/qy/qz) so {q_j,q_j+1} land in adjacent VGPRs from
// one ds_read_b128 (6 b128 per 8 j's, down from 8).
// Also: killed the 512 same-address device atomicAdds in reduce (suspected
// source of the invisible ~60us between partial=64us and total=126us) --
// reduce writes block sums to ws, new 1-block chamfer_final sums them.

#define BATCH 8
#define NPTS  8192
#define TPB   256
#define IPT   8
#define PPB   (TPB * IPT)     // 2048
#define TILES (NPTS / PPB)    // 4
#define S     32              // j-splits
#define JCH   (NPTS / S)      // 256 j's per block
#define PARTN (2 * BATCH * S * NPTS)   // floats in partial buffer (16 MB)

__device__ inline float min3f(float a, float b, float c) {
    float d;
    asm("v_min3_f32 %0, %1, %2, %3" : "=v"(d) : "v"(a), "v"(b), "v"(c));
    return d;
}

__device__ inline float2 pkfma(float2 a, float2 b, float2 c) {
    float2 d;
    asm("v_pk_fma_f32 %0, %1, %2, %3" : "=v"(d) : "v"(a), "v"(b), "v"(c));
    return d;
}

// grid.x = 2 * BATCH * TILES * S = 2048
__global__ __launch_bounds__(TPB, 4)
void chamfer_partial(const float* __restrict__ p1, const float* __restrict__ p2,
                     float* __restrict__ partial /* [2][B][S][N] */) {
    __shared__ __align__(16) float qx[JCH];
    __shared__ __align__(16) float qy[JCH];
    __shared__ __align__(16) float qz[JCH];

    int blk   = blockIdx.x;
    int split = blk & (S - 1);      blk >>= 5;
    int tile  = blk & (TILES - 1);  blk >>= 2;
    int b     = blk & (BATCH - 1);  blk >>= 3;
    int dir   = blk;

    const float2* a  = (const float2*)(dir ? p2 : p1) + (size_t)b * NPTS;
    const float2* bp = (const float2*)(dir ? p1 : p2) + (size_t)b * NPTS + split * JCH;

    int t = threadIdx.x;

    {   // JCH == TPB: exactly one q-point per thread, SoA layout
        float2 v = bp[t];
        qx[t] = v.x;
        qy[t] = v.y;
        qz[t] = fmaf(v.x, v.x, v.y * v.y);
    }

    int pt_base = tile * PPB;
    float2 xp2[IPT], yp2[IPT];
    float m[IPT];
#pragma unroll
    for (int k = 0; k < IPT; ++k) {
        float2 v = a[pt_base + k * TPB + t];
        xp2[k] = make_float2(-2.0f * v.x, -2.0f * v.x);
        yp2[k] = make_float2(-2.0f * v.y, -2.0f * v.y);
        m[k]   = 3.0e38f;
    }

    __syncthreads();

    // 8 j's per group: 6 broadcast ds_read_b128 feed 8k x 4 pk-pairs.
    // Per k: 8 v_pk_fma_f32 + 4 v_min3_f32 for 8 pairs.
    for (int j = 0; j < JCH; j += 8) {
        float4 x03 = *(const float4*)&qx[j];
        float4 x47 = *(const float4*)&qx[j + 4];
        float4 y03 = *(const float4*)&qy[j];
        float4 y47 = *(const float4*)&qy[j + 4];
        float4 z03 = *(const float4*)&qz[j];
        float4 z47 = *(const float4*)&qz[j + 4];
        float2 x01 = make_float2(x03.x, x03.y), x23 = make_float2(x03.z, x03.w);
        float2 x45 = make_float2(x47.x, x47.y), x67 = make_float2(x47.z, x47.w);
        float2 y01 = make_float2(y03.x, y03.y), y23 = make_float2(y03.z, y03.w);
        float2 y45 = make_float2(y47.x, y47.y), y67 = make_float2(y47.z, y47.w);
        float2 z01 = make_float2(z03.x, z03.y), z23 = make_float2(z03.z, z03.w);
        float2 z45 = make_float2(z47.x, z47.y), z67 = make_float2(z47.z, z47.w);
#pragma unroll
        for (int k = 0; k < IPT; ++k) {
            float2 a01 = pkfma(yp2[k], y01, pkfma(xp2[k], x01, z01));
            float2 a23 = pkfma(yp2[k], y23, pkfma(xp2[k], x23, z23));
            float2 a45 = pkfma(yp2[k], y45, pkfma(xp2[k], x45, z45));
            float2 a67 = pkfma(yp2[k], y67, pkfma(xp2[k], x67, z67));
            m[k] = min3f(m[k], a01.x, a01.y);
            m[k] = min3f(m[k], a23.x, a23.y);
            m[k] = min3f(m[k], a45.x, a45.y);
            m[k] = min3f(m[k], a67.x, a67.y);
        }
    }

    float* outp = partial + ((size_t)((dir * BATCH + b) * S + split)) * NPTS + pt_base;
#pragma unroll
    for (int k = 0; k < IPT; ++k)
        outp[k * TPB + t] = m[k];
}

// grid.x = 2 * BATCH * NPTS / TPB = 512.  No atomics: block sum -> bsum[bid].
__global__ __launch_bounds__(TPB)
void chamfer_reduce(const float* __restrict__ p1, const float* __restrict__ p2,
                    const float* __restrict__ partial, float* __restrict__ bsum) {
    int gid   = blockIdx.x * TPB + threadIdx.x;
    int point = gid & (NPTS - 1);
    int rest  = gid >> 13;
    int b     = rest & (BATCH - 1);
    int dir   = rest >> 3;

    const float* base = partial + ((size_t)(dir * BATCH + b) * S) * NPTS + point;
    float m = base[0];
#pragma unroll
    for (int s = 1; s < S; ++s)
        m = fminf(m, base[(size_t)s * NPTS]);

    float2 v = ((const float2*)(dir ? p2 : p1))[(size_t)b * NPTS + point];
    float d = m + fmaf(v.x, v.x, v.y * v.y);

#pragma unroll
    for (int off = 32; off > 0; off >>= 1)
        d += __shfl_down(d, off, 64);

    __shared__ float wsum[TPB / 64];
    int lane = threadIdx.x & 63;
    int w    = threadIdx.x >> 6;
    if (lane == 0) wsum[w] = d;
    __syncthreads();
    if (threadIdx.x == 0)
        bsum[blockIdx.x] = wsum[0] + wsum[1] + wsum[2] + wsum[3];
}

// grid.x = 1: sum 512 block sums, write the scalar. Deterministic, no atomics.
__global__ __launch_bounds__(TPB)
void chamfer_final(const float* __restrict__ bsum, float* __restrict__ out) {
    int t = threadIdx.x;
    float s = bsum[t] + bsum[t + TPB];

#pragma unroll
    for (int off = 32; off > 0; off >>= 1)
        s += __shfl_down(s, off, 64);

    __shared__ float wsum[TPB / 64];
    int lane = t & 63;
    int w    = t >> 6;
    if (lane == 0) wsum[w] = s;
    __syncthreads();
    if (t == 0)
        *out = (wsum[0] + wsum[1] + wsum[2] + wsum[3]) * (1.0f / NPTS);
}

extern "C" void kernel_launch(void* const* d_in, const int* in_sizes, int n_in,
                              void* d_out, int out_size, void* d_ws, size_t ws_size,
                              hipStream_t stream) {
    const float* p1 = (const float*)d_in[0];
    const float* p2 = (const float*)d_in[1];
    float* out      = (float*)d_out;
    float* partial  = (float*)d_ws;            // 16 MB (32 MB ws proven in R2)
    float* bsum     = partial + PARTN;         // +2 KB for 512 block sums

    chamfer_partial<<<2 * BATCH * TILES * S, TPB, 0, stream>>>(p1, p2, partial);
    chamfer_reduce<<<2 * BATCH * NPTS / TPB, TPB, 0, stream>>>(p1, p2, partial, bsum);
    chamfer_final<<<1, TPB, 0, stream>>>(bsum, out);
}